// Round 5
// baseline (231.484 us; speedup 1.0000x reference)
//
#include <hip/hip_runtime.h>

#define GXc 96
#define GYc 96
#define RFc 24
#define Bc 8
#define Nc (GXc * GYc)          // 9216
#define Hc (GXc - 1 + RFc)      // 119
#define IN_IMG (Hc * Hc)        // 14161
#define RF2 (RFc * RFc)         // 576
#define GAMMA 0.9f
#define INV_GAMMA (1.0f / 0.9f)

#define ROWS 2                  // output rows per wave
#define WAVES_PER_BLOCK 4
#define ROWS_PER_BLOCK (ROWS * WAVES_PER_BLOCK)   // 8
#define NBLOCKS (Nc / ROWS_PER_BLOCK)             // 1152
#define KW 256                                    // k-window (floats)
#define KITERS (Nc / KW)                          // 36 (even -> unroll x2 ok)

__device__ __forceinline__ void fma_window(float acc[ROWS][Bc],
                                           const float4 p[Bc],
                                           const float4& w0, const float4& w1)
{
#pragma unroll
    for (int b = 0; b < Bc; ++b) {
        acc[0][b] += w0.x * p[b].x + w0.y * p[b].y + w0.z * p[b].z + w0.w * p[b].w;
        acc[1][b] += w1.x * p[b].x + w1.y * p[b].y + w1.z * p[b].z + w1.w * p[b].w;
    }
}

__global__ __launch_bounds__(256, 4) void cortex_fused_kernel(
    const float* __restrict__ input,   // (B, 119, 119)
    const float* __restrict__ prev,    // (B, N)
    const float* __restrict__ aw,      // (N, 576)
    const float* __restrict__ We,      // (N, N)
    const float* __restrict__ Wi,      // (N, N)
    float* __restrict__ out)           // (B, N)
{
    const int tid  = threadIdx.x;
    const int wave = tid >> 6;
    const int lane = tid & 63;
    const int rowbase = blockIdx.x * ROWS_PER_BLOCK + wave * ROWS;
    const int koff = lane << 2;        // per-lane float4 slot

    float acc[ROWS][Bc];
#pragma unroll
    for (int r = 0; r < ROWS; ++r)
#pragma unroll
        for (int b = 0; b < Bc; ++b) acc[r][b] = 0.f;

    // ---------------- afferent (local RF conv), all-lane k layout ----------
#pragma unroll
    for (int r = 0; r < ROWS; ++r) {
        const int n  = rowbase + r;
        const int gi = n / GYc;
        const int gj = n - gi * GYc;
        const float* awn = aw + (size_t)n * RF2;
        const int base = gi * Hc + gj;
#pragma unroll
        for (int t = 0; t < RF2 / 64; ++t) {   // 9 iters
            const int hw = t * 64 + lane;
            const int h  = hw / RFc;
            const int w  = hw - h * RFc;
            const float av  = awn[hw] * INV_GAMMA;
            const int  off  = base + h * Hc + w;
#pragma unroll
            for (int b = 0; b < Bc; ++b)
                acc[r][b] += input[b * IN_IMG + off] * av;
        }
    }

    // ---------------- lateral: prev @ (We - Wi)^T ---------------------------
    // Barrier-free, register double-buffered W stream with counted waits:
    // per window: issue prev(j) first, then W(j+1); the compiler's wait for
    // prev(j) is vmcnt(4), leaving the next W window in flight a full iter.
    const float* r0e = We + (size_t)(rowbase + 0) * Nc;
    const float* r1e = We + (size_t)(rowbase + 1) * Nc;
    const float* r0i = Wi + (size_t)(rowbase + 0) * Nc;
    const float* r1i = Wi + (size_t)(rowbase + 1) * Nc;

    float4 e0C, e1C, i0C, i1C, e0N, e1N, i0N, i1N;
    e0C = *(const float4*)(r0e + koff);
    e1C = *(const float4*)(r1e + koff);
    i0C = *(const float4*)(r0i + koff);
    i1C = *(const float4*)(r1i + koff);

    for (int j = 0; j < KITERS; j += 2) {
        // ---- body A: window j (C regs), prefetch j+1 into N regs ----
        {
            const int k0 = j * KW + koff;
            const int kn = k0 + KW;
            float4 p[Bc];
#pragma unroll
            for (int b = 0; b < Bc; ++b)
                p[b] = *(const float4*)(prev + b * Nc + k0);
            e0N = *(const float4*)(r0e + kn);
            e1N = *(const float4*)(r1e + kn);
            i0N = *(const float4*)(r0i + kn);
            i1N = *(const float4*)(r1i + kn);

            const float4 w0 = make_float4(e0C.x - i0C.x, e0C.y - i0C.y,
                                          e0C.z - i0C.z, e0C.w - i0C.w);
            const float4 w1 = make_float4(e1C.x - i1C.x, e1C.y - i1C.y,
                                          e1C.z - i1C.z, e1C.w - i1C.w);
            fma_window(acc, p, w0, w1);
        }
        // ---- body B: window j+1 (N regs), prefetch j+2 into C regs ----
        {
            const int k0 = (j + 1) * KW + koff;
            const int kn = (j + 2 < KITERS) ? (k0 + KW) : koff;  // clamp: harmless reload
            float4 p[Bc];
#pragma unroll
            for (int b = 0; b < Bc; ++b)
                p[b] = *(const float4*)(prev + b * Nc + k0);
            e0C = *(const float4*)(r0e + kn);
            e1C = *(const float4*)(r1e + kn);
            i0C = *(const float4*)(r0i + kn);
            i1C = *(const float4*)(r1i + kn);

            const float4 w0 = make_float4(e0N.x - i0N.x, e0N.y - i0N.y,
                                          e0N.z - i0N.z, e0N.w - i0N.w);
            const float4 w1 = make_float4(e1N.x - i1N.x, e1N.y - i1N.y,
                                          e1N.z - i1N.z, e1N.w - i1N.w);
            fma_window(acc, p, w0, w1);
        }
    }

    // ---------------- butterfly reduce + static-index epilogue -------------
#pragma unroll
    for (int r = 0; r < ROWS; ++r)
#pragma unroll
        for (int b = 0; b < Bc; ++b) {
            float v = acc[r][b];
            v += __shfl_xor(v, 1);
            v += __shfl_xor(v, 2);
            v += __shfl_xor(v, 4);
            v += __shfl_xor(v, 8);
            v += __shfl_xor(v, 16);
            v += __shfl_xor(v, 32);
            if (lane == b * ROWS + r) {          // compile-time constant per instance
                const float tot = GAMMA * v;
                out[b * Nc + rowbase + r] = tot > 0.f ? tot : 0.f;
            }
        }
}

extern "C" void kernel_launch(void* const* d_in, const int* in_sizes, int n_in,
                              void* d_out, int out_size, void* d_ws, size_t ws_size,
                              hipStream_t stream) {
    const float* input = (const float*)d_in[0];
    const float* prev  = (const float*)d_in[1];
    const float* aw    = (const float*)d_in[2];
    const float* We    = (const float*)d_in[3];
    const float* Wi    = (const float*)d_in[4];
    // d_in[5], d_in[6] are rf_x / rf_y == arange(96): identity, folded into indexing.
    float* out = (float*)d_out;

    cortex_fused_kernel<<<NBLOCKS, 256, 0, stream>>>(input, prev, aw, We, Wi, out);
}

// Round 6
// 161.117 us; speedup vs baseline: 1.4367x; 1.4367x over previous
//
#include <hip/hip_runtime.h>

#define GXc 96
#define GYc 96
#define RFc 24
#define Bc 8
#define Nc (GXc * GYc)          // 9216
#define Hc (GXc - 1 + RFc)      // 119
#define IN_IMG (Hc * Hc)        // 14161
#define RF2 (RFc * RFc)         // 576
#define GAMMA 0.9f
#define INV_GAMMA (1.0f / 0.9f)

#define ROWS 2                  // output rows per wave
#define RPB 4                   // rows per block (2 rowpairs x 2 k-halves = 4 waves)
#define NBLOCKS (Nc / RPB)      // 2304 -> 9 blocks/CU exactly
#define KHALF (Nc / 2)          // 4608
#define KW 256                  // k-window (floats) = 64 lanes x float4
#define JITERS (KHALF / KW)     // 18 (even -> unroll x2 ok)

__device__ __forceinline__ float dot4(float4 a, float4 b) {
    return a.x * b.x + a.y * b.y + a.z * b.z + a.w * b.w;
}

__global__ __launch_bounds__(256) void cortex_fused_kernel(
    const float* __restrict__ input,   // (B, 119, 119)
    const float* __restrict__ prev,    // (B, N)
    const float* __restrict__ aw,      // (N, 576)
    const float* __restrict__ We,      // (N, N)
    const float* __restrict__ Wi,      // (N, N)
    float* __restrict__ out)           // (B, N)
{
    __shared__ float red[2][16];       // cross-k-half reduction, 128 B

    const int tid     = threadIdx.x;
    const int wave    = tid >> 6;
    const int lane    = tid & 63;
    const int rowpair = wave >> 1;     // 0..1: which pair of rows
    const int khalf   = wave & 1;      // 0..1: which half of K
    const int rowbase = blockIdx.x * RPB + rowpair * ROWS;
    const int koff    = lane << 2;
    const int kbase   = khalf * KHALF;

    float acc[ROWS][Bc];
#pragma unroll
    for (int r = 0; r < ROWS; ++r)
#pragma unroll
        for (int b = 0; b < Bc; ++b) acc[r][b] = 0.f;

    // ---------------- afferent (local RF conv): khalf==0 waves only --------
    if (khalf == 0) {
#pragma unroll
        for (int r = 0; r < ROWS; ++r) {
            const int n  = rowbase + r;
            const int gi = n / GYc;
            const int gj = n - gi * GYc;
            const float* awn = aw + (size_t)n * RF2;
            const int base = gi * Hc + gj;
#pragma unroll
            for (int t = 0; t < RF2 / 64; ++t) {   // 9 iters
                const int hw = t * 64 + lane;
                const int h  = hw / RFc;
                const int w  = hw - h * RFc;
                const float av = awn[hw] * INV_GAMMA;
                const int off  = base + h * Hc + w;
#pragma unroll
                for (int b = 0; b < Bc; ++b)
                    acc[r][b] += input[b * IN_IMG + off] * av;
            }
        }
    }

    // ---------------- lateral: prev @ (We - Wi)^T over this wave's k-half --
    // Barrier-free. Per body: 8 p loads FIRST, then 4 W-next loads (vmcnt is
    // in-order, so p-waits resolve at vmcnt(4) leaving W-next in flight a
    // full body), then FMAs with the CURRENT W registers.
    const float* r0e = We + (size_t)(rowbase + 0) * Nc + kbase;
    const float* r1e = We + (size_t)(rowbase + 1) * Nc + kbase;
    const float* r0i = Wi + (size_t)(rowbase + 0) * Nc + kbase;
    const float* r1i = Wi + (size_t)(rowbase + 1) * Nc + kbase;
    const float* pb  = prev + kbase;

    float4 e0C = *(const float4*)(r0e + koff);
    float4 e1C = *(const float4*)(r1e + koff);
    float4 i0C = *(const float4*)(r0i + koff);
    float4 i1C = *(const float4*)(r1i + koff);
    float4 e0N, e1N, i0N, i1N;

    for (int j = 0; j < JITERS; j += 2) {
        // ---- body A: consume C (window j), prefetch window j+1 into N ----
        {
            const int k0 = j * KW + koff;
            const int kn = k0 + KW;
            const float4 p0 = *(const float4*)(pb + 0 * Nc + k0);
            const float4 p1 = *(const float4*)(pb + 1 * Nc + k0);
            const float4 p2 = *(const float4*)(pb + 2 * Nc + k0);
            const float4 p3 = *(const float4*)(pb + 3 * Nc + k0);
            const float4 p4 = *(const float4*)(pb + 4 * Nc + k0);
            const float4 p5 = *(const float4*)(pb + 5 * Nc + k0);
            const float4 p6 = *(const float4*)(pb + 6 * Nc + k0);
            const float4 p7 = *(const float4*)(pb + 7 * Nc + k0);
            e0N = *(const float4*)(r0e + kn);
            e1N = *(const float4*)(r1e + kn);
            i0N = *(const float4*)(r0i + kn);
            i1N = *(const float4*)(r1i + kn);
            const float4 w0 = make_float4(e0C.x - i0C.x, e0C.y - i0C.y,
                                          e0C.z - i0C.z, e0C.w - i0C.w);
            const float4 w1 = make_float4(e1C.x - i1C.x, e1C.y - i1C.y,
                                          e1C.z - i1C.z, e1C.w - i1C.w);
            acc[0][0] += dot4(w0, p0);  acc[1][0] += dot4(w1, p0);
            acc[0][1] += dot4(w0, p1);  acc[1][1] += dot4(w1, p1);
            acc[0][2] += dot4(w0, p2);  acc[1][2] += dot4(w1, p2);
            acc[0][3] += dot4(w0, p3);  acc[1][3] += dot4(w1, p3);
            acc[0][4] += dot4(w0, p4);  acc[1][4] += dot4(w1, p4);
            acc[0][5] += dot4(w0, p5);  acc[1][5] += dot4(w1, p5);
            acc[0][6] += dot4(w0, p6);  acc[1][6] += dot4(w1, p6);
            acc[0][7] += dot4(w0, p7);  acc[1][7] += dot4(w1, p7);
        }
        // ---- body B: consume N (window j+1), prefetch window j+2 into C --
        {
            const int k1 = (j + 1) * KW + koff;
            const int kn = (j + 2 < JITERS) ? (k1 + KW) : koff;  // clamped reload
            const float4 p0 = *(const float4*)(pb + 0 * Nc + k1);
            const float4 p1 = *(const float4*)(pb + 1 * Nc + k1);
            const float4 p2 = *(const float4*)(pb + 2 * Nc + k1);
            const float4 p3 = *(const float4*)(pb + 3 * Nc + k1);
            const float4 p4 = *(const float4*)(pb + 4 * Nc + k1);
            const float4 p5 = *(const float4*)(pb + 5 * Nc + k1);
            const float4 p6 = *(const float4*)(pb + 6 * Nc + k1);
            const float4 p7 = *(const float4*)(pb + 7 * Nc + k1);
            e0C = *(const float4*)(r0e + kn);
            e1C = *(const float4*)(r1e + kn);
            i0C = *(const float4*)(r0i + kn);
            i1C = *(const float4*)(r1i + kn);
            const float4 w0 = make_float4(e0N.x - i0N.x, e0N.y - i0N.y,
                                          e0N.z - i0N.z, e0N.w - i0N.w);
            const float4 w1 = make_float4(e1N.x - i1N.x, e1N.y - i1N.y,
                                          e1N.z - i1N.z, e1N.w - i1N.w);
            acc[0][0] += dot4(w0, p0);  acc[1][0] += dot4(w1, p0);
            acc[0][1] += dot4(w0, p1);  acc[1][1] += dot4(w1, p1);
            acc[0][2] += dot4(w0, p2);  acc[1][2] += dot4(w1, p2);
            acc[0][3] += dot4(w0, p3);  acc[1][3] += dot4(w1, p3);
            acc[0][4] += dot4(w0, p4);  acc[1][4] += dot4(w1, p4);
            acc[0][5] += dot4(w0, p5);  acc[1][5] += dot4(w1, p5);
            acc[0][6] += dot4(w0, p6);  acc[1][6] += dot4(w1, p6);
            acc[0][7] += dot4(w0, p7);  acc[1][7] += dot4(w1, p7);
        }
    }

    // ---------------- butterfly reduce (static indexing only) --------------
    float myv = 0.f;
#pragma unroll
    for (int r = 0; r < ROWS; ++r)
#pragma unroll
        for (int b = 0; b < Bc; ++b) {
            float v = acc[r][b];
            v += __shfl_xor(v, 1);
            v += __shfl_xor(v, 2);
            v += __shfl_xor(v, 4);
            v += __shfl_xor(v, 8);
            v += __shfl_xor(v, 16);
            v += __shfl_xor(v, 32);
            if (lane == b * ROWS + r) myv = v;   // compile-time (r,b) per instance
        }

    // ---------------- cross-k-half reduction + epilogue --------------------
    if (khalf == 1 && lane < 16) red[rowpair][lane] = myv;
    __syncthreads();
    if (khalf == 0 && lane < 16) {
        const int b = lane >> 1;
        const int r = lane & 1;
        const float tot = GAMMA * (myv + red[rowpair][lane]);
        out[b * Nc + rowbase + r] = tot > 0.f ? tot : 0.f;
    }
}

extern "C" void kernel_launch(void* const* d_in, const int* in_sizes, int n_in,
                              void* d_out, int out_size, void* d_ws, size_t ws_size,
                              hipStream_t stream) {
    const float* input = (const float*)d_in[0];
    const float* prev  = (const float*)d_in[1];
    const float* aw    = (const float*)d_in[2];
    const float* We    = (const float*)d_in[3];
    const float* Wi    = (const float*)d_in[4];
    // d_in[5], d_in[6] are rf_x / rf_y == arange(96): identity, folded into indexing.
    float* out = (float*)d_out;

    cortex_fused_kernel<<<NBLOCKS, 256, 0, stream>>>(input, prev, aw, We, Wi, out);
}

// Round 7
// 156.561 us; speedup vs baseline: 1.4786x; 1.0291x over previous
//
#include <hip/hip_runtime.h>

#define GXc 96
#define GYc 96
#define RFc 24
#define Bc 8
#define Nc (GXc * GYc)          // 9216
#define Hc (GXc - 1 + RFc)      // 119
#define IN_IMG (Hc * Hc)        // 14161
#define RF2 (RFc * RFc)         // 576
#define GAMMA 0.9f
#define INV_GAMMA (1.0f / 0.9f)

#define ROWS 2                  // output rows per wave
#define WPB 4                   // waves per block
#define RPB (ROWS * WPB)        // 8 rows per block
#define NBLOCKS (Nc / RPB)      // 1152
#define KW 256                  // k-window (floats) = 64 lanes x float4
#define NWIN (Nc / KW)          // 36

__device__ __forceinline__ float dot4(float4 a, float4 b) {
    return a.x * b.x + a.y * b.y + a.z * b.z + a.w * b.w;
}

// One pipeline body: consume window J (W regs WCUR + LDS p slot SR),
// prefetch window J+2 (W -> WN2 regs, p -> LDS slot SW).
// Raw barrier with lgkmcnt-only wait: vmcnt NEVER drains below the
// 2-window prefetch depth (12 outstanding vmem ops in steady state).
#define BODY(J, SR, SW, WCUR, WN2, PREF)                                      \
  {                                                                           \
    float4 q0, q1;                                                            \
    if (PREF) {                                                               \
      const int k2 = ((J) + 2) * KW + koff;                                   \
      q0 = *(const float4*)(prev + sb0 * Nc + k2);                            \
      q1 = *(const float4*)(prev + sb1 * Nc + k2);                            \
      WN2[0] = *(const float4*)(r0e + k2);                                    \
      WN2[1] = *(const float4*)(r1e + k2);                                    \
      WN2[2] = *(const float4*)(r0i + k2);                                    \
      WN2[3] = *(const float4*)(r1i + k2);                                    \
    }                                                                         \
    __builtin_amdgcn_sched_barrier(0);                                        \
    {                                                                         \
      const float4 w0 = make_float4(WCUR[0].x - WCUR[2].x,                    \
                                    WCUR[0].y - WCUR[2].y,                    \
                                    WCUR[0].z - WCUR[2].z,                    \
                                    WCUR[0].w - WCUR[2].w);                   \
      const float4 w1 = make_float4(WCUR[1].x - WCUR[3].x,                    \
                                    WCUR[1].y - WCUR[3].y,                    \
                                    WCUR[1].z - WCUR[3].z,                    \
                                    WCUR[1].w - WCUR[3].w);                   \
      _Pragma("unroll")                                                       \
      for (int b = 0; b < Bc; ++b) {                                          \
        const float4 pb4 = *(const float4*)&pv[SR][b][koff];                  \
        acc[0][b] += dot4(w0, pb4);                                           \
        acc[1][b] += dot4(w1, pb4);                                           \
      }                                                                       \
    }                                                                         \
    __builtin_amdgcn_sched_barrier(0);                                        \
    if (PREF) {                                                               \
      *(float4*)&pv[SW][sb0][koff] = q0;                                      \
      *(float4*)&pv[SW][sb1][koff] = q1;                                      \
    }                                                                         \
    asm volatile("s_waitcnt lgkmcnt(0)" ::: "memory");                        \
    __builtin_amdgcn_s_barrier();                                             \
  }

__global__ __launch_bounds__(256) void cortex_fused_kernel(
    const float* __restrict__ input,   // (B, 119, 119)
    const float* __restrict__ prev,    // (B, N)
    const float* __restrict__ aw,      // (N, 576)
    const float* __restrict__ We,      // (N, N)
    const float* __restrict__ Wi,      // (N, N)
    float* __restrict__ out)           // (B, N)
{
    __shared__ float pv[3][Bc][KW];    // triple-buffered p windows, 24 KB

    const int tid  = threadIdx.x;
    const int wave = tid >> 6;
    const int lane = tid & 63;
    const int rowbase = blockIdx.x * RPB + wave * ROWS;
    const int koff = lane << 2;
    const int sb0 = wave * 2;          // this wave stages these 2 batches
    const int sb1 = wave * 2 + 1;

    float acc[ROWS][Bc];
#pragma unroll
    for (int r = 0; r < ROWS; ++r)
#pragma unroll
        for (int b = 0; b < Bc; ++b) acc[r][b] = 0.f;

    // ---------------- afferent (local RF conv), all-lane k layout ----------
#pragma unroll
    for (int r = 0; r < ROWS; ++r) {
        const int n  = rowbase + r;
        const int gi = n / GYc;
        const int gj = n - gi * GYc;
        const float* awn = aw + (size_t)n * RF2;
        const int base = gi * Hc + gj;
#pragma unroll
        for (int t = 0; t < RF2 / 64; ++t) {   // 9 iters
            const int hw = t * 64 + lane;
            const int h  = hw / RFc;
            const int w  = hw - h * RFc;
            const float av = awn[hw] * INV_GAMMA;
            const int off  = base + h * Hc + w;
#pragma unroll
            for (int b = 0; b < Bc; ++b)
                acc[r][b] += input[b * IN_IMG + off] * av;
        }
    }

    // ---------------- lateral: prev @ (We - Wi)^T, 2-deep pipeline ---------
    const float* r0e = We + (size_t)(rowbase + 0) * Nc;
    const float* r1e = We + (size_t)(rowbase + 1) * Nc;
    const float* r0i = Wi + (size_t)(rowbase + 0) * Nc;
    const float* r1i = Wi + (size_t)(rowbase + 1) * Nc;

    float4 wA[4], wB[4], wCr[4];

    // prologue: W(0)->wA, W(1)->wB; p(0)->pv[0], p(1)->pv[1]
    {
        float4 q0 = *(const float4*)(prev + sb0 * Nc + koff);
        float4 q1 = *(const float4*)(prev + sb1 * Nc + koff);
        wA[0] = *(const float4*)(r0e + koff);
        wA[1] = *(const float4*)(r1e + koff);
        wA[2] = *(const float4*)(r0i + koff);
        wA[3] = *(const float4*)(r1i + koff);
        float4 q2 = *(const float4*)(prev + sb0 * Nc + KW + koff);
        float4 q3 = *(const float4*)(prev + sb1 * Nc + KW + koff);
        wB[0] = *(const float4*)(r0e + KW + koff);
        wB[1] = *(const float4*)(r1e + KW + koff);
        wB[2] = *(const float4*)(r0i + KW + koff);
        wB[3] = *(const float4*)(r1i + KW + koff);
        *(float4*)&pv[0][sb0][koff] = q0;
        *(float4*)&pv[0][sb1][koff] = q1;
        *(float4*)&pv[1][sb0][koff] = q2;
        *(float4*)&pv[1][sb1][koff] = q3;
        asm volatile("s_waitcnt lgkmcnt(0)" ::: "memory");
        __builtin_amdgcn_s_barrier();
    }

    // steady state: j = 0..32 (11 x 3 bodies), all with prefetch of j+2
    for (int t = 0; t < 11; ++t) {
        const int j = 3 * t;
        BODY(j,     0, 2, wA,  wCr, true);
        BODY(j + 1, 1, 0, wB,  wA,  true);
        BODY(j + 2, 2, 1, wCr, wB,  true);
    }
    // tail: j = 33 (prefetch 35), 34, 35 (no prefetch)
    BODY(33, 0, 2, wA,  wCr, true);
    BODY(34, 1, 0, wB,  wA,  false);
    BODY(35, 2, 1, wCr, wB,  false);

    // ---------------- butterfly reduce + static-index epilogue -------------
#pragma unroll
    for (int r = 0; r < ROWS; ++r)
#pragma unroll
        for (int b = 0; b < Bc; ++b) {
            float v = acc[r][b];
            v += __shfl_xor(v, 1);
            v += __shfl_xor(v, 2);
            v += __shfl_xor(v, 4);
            v += __shfl_xor(v, 8);
            v += __shfl_xor(v, 16);
            v += __shfl_xor(v, 32);
            if (lane == b * ROWS + r) {          // compile-time (r,b) per instance
                const float tot = GAMMA * v;
                out[b * Nc + rowbase + r] = tot > 0.f ? tot : 0.f;
            }
        }
}

extern "C" void kernel_launch(void* const* d_in, const int* in_sizes, int n_in,
                              void* d_out, int out_size, void* d_ws, size_t ws_size,
                              hipStream_t stream) {
    const float* input = (const float*)d_in[0];
    const float* prev  = (const float*)d_in[1];
    const float* aw    = (const float*)d_in[2];
    const float* We    = (const float*)d_in[3];
    const float* Wi    = (const float*)d_in[4];
    // d_in[5], d_in[6] are rf_x / rf_y == arange(96): identity, folded into indexing.
    float* out = (float*)d_out;

    cortex_fused_kernel<<<NBLOCKS, 256, 0, stream>>>(input, prev, aw, We, Wi, out);
}